// Round 19
// baseline (143.489 us; speedup 1.0000x reference)
//
#include <hip/hip_runtime.h>
#include <math.h>

#define DEVINL __device__ __forceinline__

// Forced VOP3 abs-modifier add: dst = |a| + |b| in ONE v_add_f32.
DEVINL float absadd(float a, float b) {
  float t;
  asm("v_add_f32 %0, |%1|, |%2|" : "=v"(t) : "v"(a), "v"(b));
  return t;
}

// Deterministic block reduction of two double accumulators.
template<int NWAVES>
DEVINL void block_reduce_2d(double& a, double& b) {
  #pragma unroll
  for (int off = 32; off > 0; off >>= 1) {
    a += __shfl_down(a, off, 64);
    b += __shfl_down(b, off, 64);
  }
  __shared__ double sa[NWAVES], sb[NWAVES];
  const int tid = threadIdx.x;
  const int wid = tid >> 6;
  if ((tid & 63) == 0) { sa[wid] = a; sb[wid] = b; }
  __syncthreads();
  if (tid == 0) {
    double ta = 0.0, tb = 0.0;
    #pragma unroll
    for (int w = 0; w < NWAVES; ++w) { ta += sa[w]; tb += sb[w]; }
    a = ta; b = tb;
  }
}

// ---------------- Layer 1: x(16,1,196,3) * w1(128,1,6,1) s=(2,1) -> h1(16,128,96,3), fused BN+ReLU
__global__ __launch_bounds__(256) void k_conv1(
    const float* __restrict__ x, const float* __restrict__ w1,
    const float* __restrict__ g1, const float* __restrict__ b1,
    float* __restrict__ h1) {
  __shared__ float xlds[9408];          // whole x, 37.6KB
  const int co = blockIdx.x;    // 128
  const int tid = threadIdx.x;  // 256
  {
    float4* xd = (float4*)xlds;
    const float4* xs = (const float4*)x;
    #pragma unroll
    for (int k = 0; k < 10; ++k) {
      const int f = tid + k * 256;
      if (f < 2352) xd[f] = xs[f];
    }
  }
  float wv[6];
  #pragma unroll
  for (int i = 0; i < 6; ++i) wv[i] = w1[co * 6 + i];
  __syncthreads();

  float vals[18];               // 4608 positions / 256 threads
  double s = 0.0, sq = 0.0;
  #pragma unroll
  for (int k = 0; k < 18; ++k) {
    const int p = tid + k * 256;
    const int n = p / 288;
    const int r = p - n * 288;
    const int ho = r / 3;
    const int wo = r - ho * 3;
    const float* xb = xlds + n * 588 + (2 * ho) * 3 + wo;
    float e0 = xb[0]  - wv[0];
    float e1 = xb[3]  - wv[1];
    float e2 = xb[6]  - wv[2];
    float e3 = xb[9]  - wv[3];
    float e4 = xb[12] - wv[4];
    float e5 = xb[15] - wv[5];
    const float t0 = absadd(e0, e1);
    const float t1 = absadd(e2, e3);
    const float t2 = absadd(e4, e5);
    const float v = -((t0 + t1) + t2);
    vals[k] = v;
    s += (double)v;
    sq += (double)v * (double)v;
  }
  block_reduce_2d<4>(s, sq);
  __shared__ float ssc, ssh;
  if (tid == 0) {
    const double mean = s * (1.0 / 4608.0);
    const double var  = sq * (1.0 / 4608.0) - mean * mean;
    const float rstd = (float)rsqrt(var + 1e-5);
    const float sc = g1[co] * rstd;
    ssc = sc;
    ssh = b1[co] - (float)mean * sc;
  }
  __syncthreads();
  const float sc = ssc, sh = ssh;
  #pragma unroll
  for (int k = 0; k < 18; ++k) {
    const int p = tid + k * 256;
    const int n = p / 288;
    const int r = p - n * 288;
    const int ho = r / 3;
    const int wo = r - ho * 3;
    h1[((n * 128 + co) * 96 + ho) * 3 + wo] = fmaxf(0.f, fmaf(vals[k], sc, sh));
  }
}

// ---------------- Layer 2 partial: h1(16,128,96,3) * w2(256,128,6,1) s=(2,1)
// Grid 1024 = 2nh x 2hoh x 32cg(8co) x 8kc(16ci). 256 threads = 4 waves; wave w owns
// ci kc*16+w*4..+3 with its OWN single-buffer LDS (wave-synchronous, no in-loop barrier).
// Lane = (n in 8, co in 8) owns a 23-ho half-column (69 outputs); x row read once per ci
// via sliding 18-float window. End: waves 1-3 pass acc in 3 chunks of 23 via xbuf reuse.
__global__ __launch_bounds__(256) void k_conv2p(
    const float* __restrict__ h1, const float* __restrict__ w2,
    float* __restrict__ part2) {
  __shared__ float wlds[1024];          // [ci 16][co 8][8 pad], wave w inits quarter w
  __shared__ float2 xbuf4[4][616];      // per-wave [8n][77 pad]; reused as handoff buf
  const int bx = blockIdx.x;
  const int kc = bx & 7;
  const int rbx = bx >> 3;
  const int cg = rbx & 31;
  const int rbx2 = rbx >> 5;
  const int hoh = rbx2 & 1;
  const int nh = rbx2 >> 1;
  const int co0 = cg * 8, ci0 = kc * 16, n0 = nh * 8;
  const int tid = threadIdx.x;          // 256
  const int wvid = tid >> 6;            // wave 0..3
  const int lane = tid & 63;
  // each wave inits ITS quarter of wlds (ci wvid*4..+3) -> no barrier needed
  #pragma unroll
  for (int k = 0; k < 4; ++k) {
    const int f = wvid * 256 + lane + k * 64;
    const int cil = f >> 6, rem = f & 63, c = rem >> 3, kk = rem & 7;
    wlds[f] = (kk < 6) ? w2[(co0 + c) * 768 + (ci0 + cil) * 6 + kk] : 0.f;
  }
  const int n = lane >> 3, co = lane & 7;

  // stage slots: 600 f2 = 8n x 75 (rows 46hoh..46hoh+49). Slots k<9 full, k=9 lane<24.
  int s_lds[10], s_g[10];
  const bool v10 = lane < 24;
  #pragma unroll
  for (int k = 0; k < 10; ++k) {
    const int f = lane + k * 64;
    const int nn = f / 75, j = f - nn * 75;
    s_lds[k] = nn * 77 + j;
    s_g[k]   = (n0 + nn) * 18432 + 69 * hoh + j;   // + ci*144 at load
  }
  const float2* h1v = (const float2*)h1;
  const int cibase = ci0 + wvid * 4;

  float acc[69];
  #pragma unroll
  for (int i = 0; i < 69; ++i) acc[i] = 0.f;

  float2 r[10];
  #pragma unroll
  for (int k = 0; k < 9; ++k) r[k] = h1v[s_g[k] + cibase * 144];
  if (v10) r[9] = h1v[s_g[9] + cibase * 144];

  const float2* xrow2 = xbuf4[wvid] + n * 77;
  const float4* wl4 = (const float4*)wlds;

  #pragma unroll 1
  for (int cil = 0; cil < 4; ++cil) {
    // wave-synchronous single buffer: prior reads precede these writes in program order
    #pragma unroll
    for (int k = 0; k < 9; ++k) xbuf4[wvid][s_lds[k]] = r[k];
    if (v10) xbuf4[wvid][s_lds[9]] = r[9];
    if (cil + 1 < 4) {                  // prefetch next ci into regs
      #pragma unroll
      for (int k = 0; k < 9; ++k) r[k] = h1v[s_g[k] + (cibase + cil + 1) * 144];
      if (v10) r[9] = h1v[s_g[9] + (cibase + cil + 1) * 144];
    }
    const int cl = wvid * 4 + cil;
    const float4 wa = wl4[(cl * 8 + co) * 2];
    const float4 wb = wl4[(cl * 8 + co) * 2 + 1];
    const float wv[6] = {wa.x, wa.y, wa.z, wa.w, wb.x, wb.y};
    // sliding 18-float window (rows 2h..2h+5 of the half-column)
    float xf[18];
    #pragma unroll
    for (int t = 0; t < 9; ++t) {
      const float2 q = xrow2[t];
      xf[2 * t] = q.x; xf[2 * t + 1] = q.y;
    }
    #pragma unroll
    for (int h = 0; h < 23; ++h) {
      if (h > 0) {                      // slide 2 rows: keep 12 floats, read 3 f2
        #pragma unroll
        for (int t = 0; t < 12; ++t) xf[t] = xf[t + 6];
        #pragma unroll
        for (int t = 0; t < 3; ++t) {
          const float2 q = xrow2[3 * h + 6 + t];
          xf[12 + 2 * t] = q.x; xf[13 + 2 * t] = q.y;
        }
      }
      #pragma unroll
      for (int wo = 0; wo < 3; ++wo) {
        float e0 = xf[0  + wo] - wv[0];
        float e1 = xf[3  + wo] - wv[1];
        float e2 = xf[6  + wo] - wv[2];
        float e3 = xf[9  + wo] - wv[3];
        float e4 = xf[12 + wo] - wv[4];
        float e5 = xf[15 + wo] - wv[5];
        const float t0 = absadd(e0, e1);
        const float t1 = absadd(e2, e3);
        const float t2 = absadd(e4, e5);
        acc[h * 3 + wo] += (t0 + t1) + t2;
      }
    }
  }
  // cross-wave reduction reusing xbuf4 region: 3 chunks of 23, waves 1-3 -> wave0
  __syncthreads();                      // all waves done with xbuf
  float* accb = (float*)xbuf4;          // 3 regions x 64 lanes x 24 floats = 18432 B
  #pragma unroll 1
  for (int chunk = 0; chunk < 3; ++chunk) {
    if (wvid > 0) {
      #pragma unroll
      for (int i = 0; i < 23; ++i)
        accb[((wvid - 1) * 64 + lane) * 24 + i] = acc[chunk * 23 + i];
    }
    __syncthreads();
    if (wvid == 0) {
      #pragma unroll
      for (int w = 0; w < 3; ++w)
        #pragma unroll
        for (int i = 0; i < 23; ++i)
          acc[chunk * 23 + i] += accb[(w * 64 + lane) * 24 + i];
    }
    __syncthreads();
  }
  if (wvid == 0) {
    float* dst = part2 + (size_t)(kc * 256 + co0 + co) * 2208 + (n0 + n) * 138 + 69 * hoh;
    #pragma unroll
    for (int i = 0; i < 69; ++i) dst[i] = acc[i];
  }
}

// ---------------- Layer 2 combine: sum 8 K-partials, BN stats + apply -> h2(16,256,46,3)
__global__ __launch_bounds__(384) void k_combine2(
    const float* __restrict__ part2, const float* __restrict__ g2,
    const float* __restrict__ b2, float* __restrict__ h2) {
  const int co = blockIdx.x;    // 256
  const int tid = threadIdx.x;  // 384, active 368, 6 pos each
  const bool active = tid < 368;
  float v[6];
  double s = 0.0, sq = 0.0;
  #pragma unroll
  for (int k = 0; k < 6; ++k) {
    float sum = 0.f;
    if (active) {
      const int p = tid + k * 368;
      #pragma unroll
      for (int kc = 0; kc < 8; ++kc)
        sum += part2[(size_t)(kc * 256 + co) * 2208 + p];
    }
    const float val = -sum;
    v[k] = val;
    if (active) { s += (double)val; sq += (double)val * (double)val; }
  }
  block_reduce_2d<6>(s, sq);
  __shared__ float ssc, ssh;
  if (tid == 0) {
    const double mean = s * (1.0 / 2208.0);
    const double var  = sq * (1.0 / 2208.0) - mean * mean;
    const float rstd = (float)rsqrt(var + 1e-5);
    const float sc = g2[co] * rstd;
    ssc = sc;
    ssh = b2[co] - (float)mean * sc;
  }
  __syncthreads();
  if (active) {
    const float sc = ssc, sh = ssh;
    #pragma unroll
    for (int k = 0; k < 6; ++k) {
      const int p = tid + k * 368;
      const int n = p / 138, rem = p - n * 138;
      h2[n * 35328 + co * 138 + rem] = fmaxf(0.f, fmaf(v[k], sc, sh));
    }
  }
}

// ---------------- Layer 3 partial: h2(16,256,46,3) * w3(384,256,6,2) s=(2,1)
// Grid 1536 = 2nh x 48cg(8co) x 16kc(16ci). 256 threads = 4 waves; wave w owns ci w*4..+3
// with its OWN single-buffer LDS (wave-synchronous). Lane = (n in 8, co in 8) owns the FULL
// 21ho x 2wo column; x row read once per ci via sliding 30-float window.
// End: waves 1-3 pass acc in 2 chunks of 21 via xbuf reuse; wave0 sums + stores.
__global__ __launch_bounds__(256) void k_conv3p(
    const float* __restrict__ h2, const float* __restrict__ w3,
    float* __restrict__ part3) {
  __shared__ float wlds[1536];          // [ci 16][co 8][12], wave w inits quarter w
  __shared__ float2 xbuf4[4][560];      // per-wave [8n][70 pad]; reused as handoff buf
  const int bx = blockIdx.x;
  const int kc = bx & 15;
  const int rbx = bx >> 4;
  const int cg = rbx % 48;
  const int nh = rbx / 48;              // 0..1
  const int co0 = cg * 8, ci0 = kc * 16, n0 = nh * 8;
  const int tid = threadIdx.x;          // 256
  const int wvid = tid >> 6;            // wave 0..3
  const int lane = tid & 63;
  // each wave inits ITS quarter of wlds (ci wvid*4..+3)
  #pragma unroll
  for (int k = 0; k < 6; ++k) {
    const int f = wvid * 384 + lane + k * 64;
    const int cil = f / 96, rem = f - cil * 96, c = rem / 12, kk = rem - c * 12;
    wlds[f] = w3[(co0 + c) * 3072 + (ci0 + cil) * 12 + kk];
  }
  const int n = lane >> 3, co = lane & 7;

  int s_lds[9], s_g[9];
  const bool v9 = lane < 40;
  #pragma unroll
  for (int k = 0; k < 9; ++k) {
    const int f = lane + k * 64;
    const int nn = f / 69, j = f - nn * 69;
    s_lds[k] = nn * 70 + j;
    s_g[k]   = (n0 + nn) * 17664 + j;   // + ci*69 at load
  }
  const float2* h2v = (const float2*)h2;
  const int cibase = ci0 + wvid * 4;

  float acc[42];
  #pragma unroll
  for (int i = 0; i < 42; ++i) acc[i] = 0.f;

  float2 r[9];
  #pragma unroll
  for (int k = 0; k < 8; ++k) r[k] = h2v[s_g[k] + cibase * 69];
  if (v9) r[8] = h2v[s_g[8] + cibase * 69];

  const float2* xrow2 = xbuf4[wvid] + n * 70;
  const float4* wl4 = (const float4*)wlds;

  #pragma unroll 1
  for (int cil = 0; cil < 4; ++cil) {
    #pragma unroll
    for (int k = 0; k < 8; ++k) xbuf4[wvid][s_lds[k]] = r[k];
    if (v9) xbuf4[wvid][s_lds[8]] = r[8];
    if (cil + 1 < 4) {
      #pragma unroll
      for (int k = 0; k < 8; ++k) r[k] = h2v[s_g[k] + (cibase + cil + 1) * 69];
      if (v9) r[8] = h2v[s_g[8] + (cibase + cil + 1) * 69];
    }
    const int cl = wvid * 4 + cil;
    const float4 w0 = wl4[(cl * 8 + co) * 3];
    const float4 w1 = wl4[(cl * 8 + co) * 3 + 1];
    const float4 w2q = wl4[(cl * 8 + co) * 3 + 2];
    const float wv[12] = {w0.x, w0.y, w0.z, w0.w, w1.x, w1.y,
                          w1.z, w1.w, w2q.x, w2q.y, w2q.z, w2q.w};
    float xf[30];
    #pragma unroll
    for (int t = 0; t < 15; ++t) {
      const float2 q = xrow2[t];
      xf[2 * t + 0] = q.x; xf[2 * t + 1] = q.y;
    }
    #pragma unroll
    for (int hot = 0; hot < 7; ++hot) {
      #pragma unroll
      for (int h = 0; h < 3; ++h)
        #pragma unroll
        for (int wo = 0; wo < 2; ++wo) {
          float e0  = xf[(2 * h + 0) * 3 + wo]     - wv[0];
          float e1  = xf[(2 * h + 0) * 3 + wo + 1] - wv[1];
          float e2  = xf[(2 * h + 1) * 3 + wo]     - wv[2];
          float e3  = xf[(2 * h + 1) * 3 + wo + 1] - wv[3];
          float e4  = xf[(2 * h + 2) * 3 + wo]     - wv[4];
          float e5  = xf[(2 * h + 2) * 3 + wo + 1] - wv[5];
          float e6  = xf[(2 * h + 3) * 3 + wo]     - wv[6];
          float e7  = xf[(2 * h + 3) * 3 + wo + 1] - wv[7];
          float e8  = xf[(2 * h + 4) * 3 + wo]     - wv[8];
          float e9  = xf[(2 * h + 4) * 3 + wo + 1] - wv[9];
          float e10 = xf[(2 * h + 5) * 3 + wo]     - wv[10];
          float e11 = xf[(2 * h + 5) * 3 + wo + 1] - wv[11];
          const float t0 = absadd(e0, e1);
          const float t1 = absadd(e2, e3);
          const float t2 = absadd(e4, e5);
          const float t3 = absadd(e6, e7);
          const float t4 = absadd(e8, e9);
          const float t5 = absadd(e10, e11);
          acc[(3 * hot + h) * 2 + wo] += ((t0 + t1) + (t2 + t3)) + (t4 + t5);
        }
      if (hot < 6) {
        #pragma unroll
        for (int t = 0; t < 12; ++t) xf[t] = xf[t + 18];
        #pragma unroll
        for (int t = 0; t < 9; ++t) {
          const float2 q = xrow2[9 * hot + 15 + t];
          xf[12 + 2 * t] = q.x; xf[13 + 2 * t] = q.y;
        }
      }
    }
  }
  // cross-wave reduction reusing xbuf4 region: 2 chunks of 21, waves 1-3 -> wave0
  __syncthreads();                      // all waves done with xbuf
  float* accb = (float*)xbuf4;          // 3 regions x 64 lanes x 22 floats = 16896 B
  #pragma unroll 1
  for (int chunk = 0; chunk < 2; ++chunk) {
    if (wvid > 0) {
      #pragma unroll
      for (int i = 0; i < 21; ++i)
        accb[((wvid - 1) * 64 + lane) * 22 + i] = acc[chunk * 21 + i];
    }
    __syncthreads();
    if (wvid == 0) {
      #pragma unroll
      for (int w = 0; w < 3; ++w)
        #pragma unroll
        for (int i = 0; i < 21; ++i)
          acc[chunk * 21 + i] += accb[(w * 64 + lane) * 22 + i];
    }
    __syncthreads();
  }
  if (wvid == 0) {
    float2* dst = (float2*)(part3 + (size_t)(kc * 384 + co0 + co) * 672 + (n0 + n) * 42);
    #pragma unroll
    for (int k = 0; k < 21; ++k) dst[k] = make_float2(acc[2 * k], acc[2 * k + 1]);
  }
}

// ---------------- Layer 3 combine: sum 16 K-partials, BN stats + apply -> h3(16,384,21,2)
__global__ __launch_bounds__(384) void k_combine3(
    const float* __restrict__ part3, const float* __restrict__ g3,
    const float* __restrict__ b3, float* __restrict__ h3) {
  const int co = blockIdx.x;    // 384
  const int tid = threadIdx.x;  // 384, active 336, 2 pos each
  const bool active = tid < 336;
  float v[2];
  double s = 0.0, sq = 0.0;
  #pragma unroll
  for (int k = 0; k < 2; ++k) {
    float sum = 0.f;
    if (active) {
      const int p = tid + k * 336;
      #pragma unroll
      for (int kc = 0; kc < 16; ++kc)
        sum += part3[(size_t)(kc * 384 + co) * 672 + p];
    }
    const float val = -sum;
    v[k] = val;
    if (active) { s += (double)val; sq += (double)val * (double)val; }
  }
  block_reduce_2d<6>(s, sq);
  __shared__ float ssc, ssh;
  if (tid == 0) {
    const double mean = s * (1.0 / 672.0);
    const double var  = sq * (1.0 / 672.0) - mean * mean;
    const float rstd = (float)rsqrt(var + 1e-5);
    const float sc = g3[co] * rstd;
    ssc = sc;
    ssh = b3[co] - (float)mean * sc;
  }
  __syncthreads();
  if (active) {
    const float sc = ssc, sh = ssh;
    #pragma unroll
    for (int k = 0; k < 2; ++k) {
      const int p = tid + k * 336;
      const int n = p / 42, rem = p - n * 42;
      h3[n * 16128 + co * 42 + rem] = fmaxf(0.f, fmaf(v[k], sc, sh));
    }
  }
}

// ---------------- FC partial: h3(16,16128) @ Wfc(6,16128)^T, K split 4 ways
__global__ __launch_bounds__(256) void k_fcp(
    const float* __restrict__ h3, const float* __restrict__ Wfc,
    float* __restrict__ hfcp) {
  const int bx = blockIdx.x;    // 384 = 96 pairs x 4
  const int pair = bx >> 2, q = bx & 3;
  const int n = pair / 6, o = pair - n * 6;
  const float4* xr = (const float4*)(h3 + n * 16128) + q * 1008;
  const float4* wr = (const float4*)(Wfc + o * 16128) + q * 1008;
  float sacc = 0.f;
  for (int k = threadIdx.x; k < 1008; k += 256) {
    const float4 xv = xr[k];
    const float4 wv = wr[k];
    sacc += xv.x * wv.x + xv.y * wv.y + xv.z * wv.z + xv.w * wv.w;
  }
  double d = (double)sacc, dummy = 0.0;
  block_reduce_2d<4>(d, dummy);
  if (threadIdx.x == 0) hfcp[bx] = (float)d;
}

// ---------------- Final: sum FC partials + bias, LayerNorm over 96, per-row L2 norm -> out(16,6)
__global__ __launch_bounds__(128) void k_final(
    const float* __restrict__ hfcp, const float* __restrict__ bfc,
    float* __restrict__ out) {
  __shared__ float ys[96];
  __shared__ float params[2];
  const int tid = threadIdx.x;
  float v = 0.f;
  if (tid < 96) {
    v = hfcp[tid * 4 + 0] + hfcp[tid * 4 + 1] + hfcp[tid * 4 + 2] + hfcp[tid * 4 + 3]
        + bfc[tid % 6];
    ys[tid] = v;
  }
  __syncthreads();
  if (tid == 0) {
    double s = 0.0, sq = 0.0;
    for (int i = 0; i < 96; ++i) { const double t = (double)ys[i]; s += t; sq += t * t; }
    const double mu = s / 96.0;
    const double var = sq / 96.0 - mu * mu;
    params[0] = (float)mu;
    params[1] = (float)rsqrt(var + 1e-5);
  }
  __syncthreads();
  const float y = (v - params[0]) * params[1];
  __syncthreads();
  if (tid < 96) ys[tid] = y;
  __syncthreads();
  if (tid < 96) {
    const int n = tid / 6;
    float ss = 0.f;
    #pragma unroll
    for (int k = 0; k < 6; ++k) { const float t = ys[n * 6 + k]; ss += t * t; }
    const float norm = sqrtf(ss);
    out[tid] = y / fmaxf(norm, 1e-12f);
  }
}

extern "C" void kernel_launch(void* const* d_in, const int* in_sizes, int n_in,
                              void* d_out, int out_size, void* d_ws, size_t ws_size,
                              hipStream_t stream) {
  const float* x   = (const float*)d_in[0];
  const float* w1  = (const float*)d_in[1];
  const float* g1  = (const float*)d_in[2];
  const float* b1  = (const float*)d_in[3];
  const float* w2  = (const float*)d_in[4];
  const float* g2  = (const float*)d_in[5];
  const float* b2  = (const float*)d_in[6];
  const float* w3  = (const float*)d_in[7];
  const float* g3  = (const float*)d_in[8];
  const float* b3  = (const float*)d_in[9];
  const float* Wfc = (const float*)d_in[10];
  const float* bfc = (const float*)d_in[11];

  float* ws   = (float*)d_ws;
  float* h1   = ws;                 // 589824
  float* h2   = h1 + 589824;        // 565248
  float* h3   = h2 + 565248;        // 258048
  float* hfcp = h3 + 258048;        // 384
  float* part = hfcp + 384;         // max(8*256*2208, 16*384*672) = 4521984
  float* out  = (float*)d_out;

  k_conv1   <<<128, 256, 0, stream>>>(x, w1, g1, b1, h1);
  k_conv2p  <<<1024, 256, 0, stream>>>(h1, w2, part);
  k_combine2<<<256, 384, 0, stream>>>(part, g2, b2, h2);
  k_conv3p  <<<1536, 256, 0, stream>>>(h2, w3, part);
  k_combine3<<<384, 384, 0, stream>>>(part, g3, b3, h3);
  k_fcp     <<<384, 256, 0, stream>>>(h3, Wfc, hfcp);
  k_final   <<<1, 128, 0, stream>>>(hfcp, bfc, out);
}

// Round 20
// 105.879 us; speedup vs baseline: 1.3552x; 1.3552x over previous
//
#include <hip/hip_runtime.h>
#include <math.h>

#define DEVINL __device__ __forceinline__

// Forced VOP3 abs-modifier add: dst = |a| + |b| in ONE v_add_f32.
DEVINL float absadd(float a, float b) {
  float t;
  asm("v_add_f32 %0, |%1|, |%2|" : "=v"(t) : "v"(a), "v"(b));
  return t;
}

// Deterministic block reduction of two double accumulators.
template<int NWAVES>
DEVINL void block_reduce_2d(double& a, double& b) {
  #pragma unroll
  for (int off = 32; off > 0; off >>= 1) {
    a += __shfl_down(a, off, 64);
    b += __shfl_down(b, off, 64);
  }
  __shared__ double sa[NWAVES], sb[NWAVES];
  const int tid = threadIdx.x;
  const int wid = tid >> 6;
  if ((tid & 63) == 0) { sa[wid] = a; sb[wid] = b; }
  __syncthreads();
  if (tid == 0) {
    double ta = 0.0, tb = 0.0;
    #pragma unroll
    for (int w = 0; w < NWAVES; ++w) { ta += sa[w]; tb += sb[w]; }
    a = ta; b = tb;
  }
}

// ---------------- Layer 1: x(16,1,196,3) * w1(128,1,6,1) s=(2,1) -> h1(16,128,96,3), fused BN+ReLU
__global__ __launch_bounds__(256) void k_conv1(
    const float* __restrict__ x, const float* __restrict__ w1,
    const float* __restrict__ g1, const float* __restrict__ b1,
    float* __restrict__ h1) {
  __shared__ float xlds[9408];          // whole x, 37.6KB
  const int co = blockIdx.x;    // 128
  const int tid = threadIdx.x;  // 256
  {
    float4* xd = (float4*)xlds;
    const float4* xs = (const float4*)x;
    #pragma unroll
    for (int k = 0; k < 10; ++k) {
      const int f = tid + k * 256;
      if (f < 2352) xd[f] = xs[f];
    }
  }
  float wv[6];
  #pragma unroll
  for (int i = 0; i < 6; ++i) wv[i] = w1[co * 6 + i];
  __syncthreads();

  float vals[18];               // 4608 positions / 256 threads
  double s = 0.0, sq = 0.0;
  #pragma unroll
  for (int k = 0; k < 18; ++k) {
    const int p = tid + k * 256;
    const int n = p / 288;
    const int r = p - n * 288;
    const int ho = r / 3;
    const int wo = r - ho * 3;
    const float* xb = xlds + n * 588 + (2 * ho) * 3 + wo;
    float e0 = xb[0]  - wv[0];
    float e1 = xb[3]  - wv[1];
    float e2 = xb[6]  - wv[2];
    float e3 = xb[9]  - wv[3];
    float e4 = xb[12] - wv[4];
    float e5 = xb[15] - wv[5];
    const float t0 = absadd(e0, e1);
    const float t1 = absadd(e2, e3);
    const float t2 = absadd(e4, e5);
    const float v = -((t0 + t1) + t2);
    vals[k] = v;
    s += (double)v;
    sq += (double)v * (double)v;
  }
  block_reduce_2d<4>(s, sq);
  __shared__ float ssc, ssh;
  if (tid == 0) {
    const double mean = s * (1.0 / 4608.0);
    const double var  = sq * (1.0 / 4608.0) - mean * mean;
    const float rstd = (float)rsqrt(var + 1e-5);
    const float sc = g1[co] * rstd;
    ssc = sc;
    ssh = b1[co] - (float)mean * sc;
  }
  __syncthreads();
  const float sc = ssc, sh = ssh;
  #pragma unroll
  for (int k = 0; k < 18; ++k) {
    const int p = tid + k * 256;
    const int n = p / 288;
    const int r = p - n * 288;
    const int ho = r / 3;
    const int wo = r - ho * 3;
    h1[((n * 128 + co) * 96 + ho) * 3 + wo] = fmaxf(0.f, fmaf(vals[k], sc, sh));
  }
}

// ---------------- Layer 2 partial: h1(16,128,96,3) * w2(256,128,6,1) s=(2,1)
// Grid 1024 = 2nh x 2hoh x 32cg(8co) x 8kc(16ci). 256 threads = 4 waves; wave w owns
// ci kc*16+w*4..+3 with its OWN single-buffer LDS (wave-synchronous, no in-loop barrier).
// Lane = (n in 8, co in 8) owns a 23-ho half-column (69 outputs); x row read once per ci
// via sliding 18-float window. End handoff FULLY UNROLLED (const acc indices, no scratch).
__global__ __launch_bounds__(256) void k_conv2p(
    const float* __restrict__ h1, const float* __restrict__ w2,
    float* __restrict__ part2) {
  __shared__ float wlds[1024];          // [ci 16][co 8][8 pad], wave w inits quarter w
  __shared__ float2 xbuf4[4][616];      // per-wave [8n][77 pad]; reused as handoff buf
  const int bx = blockIdx.x;
  const int kc = bx & 7;
  const int rbx = bx >> 3;
  const int cg = rbx & 31;
  const int rbx2 = rbx >> 5;
  const int hoh = rbx2 & 1;
  const int nh = rbx2 >> 1;
  const int co0 = cg * 8, ci0 = kc * 16, n0 = nh * 8;
  const int tid = threadIdx.x;          // 256
  const int wvid = tid >> 6;            // wave 0..3
  const int lane = tid & 63;
  // each wave inits ITS quarter of wlds (ci wvid*4..+3) -> no barrier needed
  #pragma unroll
  for (int k = 0; k < 4; ++k) {
    const int f = wvid * 256 + lane + k * 64;
    const int cil = f >> 6, rem = f & 63, c = rem >> 3, kk = rem & 7;
    wlds[f] = (kk < 6) ? w2[(co0 + c) * 768 + (ci0 + cil) * 6 + kk] : 0.f;
  }
  const int n = lane >> 3, co = lane & 7;

  // stage slots: 600 f2 = 8n x 75 (rows 46hoh..46hoh+49). Slots k<9 full, k=9 lane<24.
  int s_lds[10], s_g[10];
  const bool v10 = lane < 24;
  #pragma unroll
  for (int k = 0; k < 10; ++k) {
    const int f = lane + k * 64;
    const int nn = f / 75, j = f - nn * 75;
    s_lds[k] = nn * 77 + j;
    s_g[k]   = (n0 + nn) * 18432 + 69 * hoh + j;   // + ci*144 at load
  }
  const float2* h1v = (const float2*)h1;
  const int cibase = ci0 + wvid * 4;

  float acc[69];
  #pragma unroll
  for (int i = 0; i < 69; ++i) acc[i] = 0.f;

  float2 r[10];
  #pragma unroll
  for (int k = 0; k < 9; ++k) r[k] = h1v[s_g[k] + cibase * 144];
  if (v10) r[9] = h1v[s_g[9] + cibase * 144];

  const float2* xrow2 = xbuf4[wvid] + n * 77;
  const float4* wl4 = (const float4*)wlds;

  #pragma unroll 1
  for (int cil = 0; cil < 4; ++cil) {
    // wave-synchronous single buffer: prior reads precede these writes in program order
    #pragma unroll
    for (int k = 0; k < 9; ++k) xbuf4[wvid][s_lds[k]] = r[k];
    if (v10) xbuf4[wvid][s_lds[9]] = r[9];
    if (cil + 1 < 4) {                  // prefetch next ci into regs
      #pragma unroll
      for (int k = 0; k < 9; ++k) r[k] = h1v[s_g[k] + (cibase + cil + 1) * 144];
      if (v10) r[9] = h1v[s_g[9] + (cibase + cil + 1) * 144];
    }
    const int cl = wvid * 4 + cil;
    const float4 wa = wl4[(cl * 8 + co) * 2];
    const float4 wb = wl4[(cl * 8 + co) * 2 + 1];
    const float wv[6] = {wa.x, wa.y, wa.z, wa.w, wb.x, wb.y};
    // sliding 18-float window (rows 2h..2h+5 of the half-column)
    float xf[18];
    #pragma unroll
    for (int t = 0; t < 9; ++t) {
      const float2 q = xrow2[t];
      xf[2 * t] = q.x; xf[2 * t + 1] = q.y;
    }
    #pragma unroll
    for (int h = 0; h < 23; ++h) {
      if (h > 0) {                      // slide 2 rows: keep 12 floats, read 3 f2
        #pragma unroll
        for (int t = 0; t < 12; ++t) xf[t] = xf[t + 6];
        #pragma unroll
        for (int t = 0; t < 3; ++t) {
          const float2 q = xrow2[3 * h + 6 + t];
          xf[12 + 2 * t] = q.x; xf[13 + 2 * t] = q.y;
        }
      }
      #pragma unroll
      for (int wo = 0; wo < 3; ++wo) {
        float e0 = xf[0  + wo] - wv[0];
        float e1 = xf[3  + wo] - wv[1];
        float e2 = xf[6  + wo] - wv[2];
        float e3 = xf[9  + wo] - wv[3];
        float e4 = xf[12 + wo] - wv[4];
        float e5 = xf[15 + wo] - wv[5];
        const float t0 = absadd(e0, e1);
        const float t1 = absadd(e2, e3);
        const float t2 = absadd(e4, e5);
        acc[h * 3 + wo] += (t0 + t1) + t2;
      }
    }
  }
  // cross-wave reduction reusing xbuf4 region: 3 chunks of 23, FULLY UNROLLED
  __syncthreads();                      // all waves done with xbuf
  float* accb = (float*)xbuf4;          // 3 regions x 64 lanes x 24 floats = 18432 B
  #pragma unroll
  for (int chunk = 0; chunk < 3; ++chunk) {
    if (wvid > 0) {
      #pragma unroll
      for (int i = 0; i < 23; ++i)
        accb[((wvid - 1) * 64 + lane) * 24 + i] = acc[chunk * 23 + i];
    }
    __syncthreads();
    if (wvid == 0) {
      #pragma unroll
      for (int w = 0; w < 3; ++w)
        #pragma unroll
        for (int i = 0; i < 23; ++i)
          acc[chunk * 23 + i] += accb[(w * 64 + lane) * 24 + i];
    }
    __syncthreads();
  }
  if (wvid == 0) {
    float* dst = part2 + (size_t)(kc * 256 + co0 + co) * 2208 + (n0 + n) * 138 + 69 * hoh;
    #pragma unroll
    for (int i = 0; i < 69; ++i) dst[i] = acc[i];
  }
}

// ---------------- Layer 2 combine: sum 8 K-partials, BN stats + apply -> h2(16,256,46,3)
__global__ __launch_bounds__(384) void k_combine2(
    const float* __restrict__ part2, const float* __restrict__ g2,
    const float* __restrict__ b2, float* __restrict__ h2) {
  const int co = blockIdx.x;    // 256
  const int tid = threadIdx.x;  // 384, active 368, 6 pos each
  const bool active = tid < 368;
  float v[6];
  double s = 0.0, sq = 0.0;
  #pragma unroll
  for (int k = 0; k < 6; ++k) {
    float sum = 0.f;
    if (active) {
      const int p = tid + k * 368;
      #pragma unroll
      for (int kc = 0; kc < 8; ++kc)
        sum += part2[(size_t)(kc * 256 + co) * 2208 + p];
    }
    const float val = -sum;
    v[k] = val;
    if (active) { s += (double)val; sq += (double)val * (double)val; }
  }
  block_reduce_2d<6>(s, sq);
  __shared__ float ssc, ssh;
  if (tid == 0) {
    const double mean = s * (1.0 / 2208.0);
    const double var  = sq * (1.0 / 2208.0) - mean * mean;
    const float rstd = (float)rsqrt(var + 1e-5);
    const float sc = g2[co] * rstd;
    ssc = sc;
    ssh = b2[co] - (float)mean * sc;
  }
  __syncthreads();
  if (active) {
    const float sc = ssc, sh = ssh;
    #pragma unroll
    for (int k = 0; k < 6; ++k) {
      const int p = tid + k * 368;
      const int n = p / 138, rem = p - n * 138;
      h2[n * 35328 + co * 138 + rem] = fmaxf(0.f, fmaf(v[k], sc, sh));
    }
  }
}

// ---------------- Layer 3 partial: h2(16,256,46,3) * w3(384,256,6,2) s=(2,1)
// Grid 1536 = 2nh x 48cg(8co) x 16kc(16ci). 256 threads = 4 waves; wave w owns ci w*4..+3
// with its OWN single-buffer LDS (wave-synchronous). Lane = (n in 8, co in 8) owns the FULL
// 21ho x 2wo column; x row read once per ci via sliding 30-float window.
// End handoff (2 chunks of 21) FULLY UNROLLED (const acc indices, no scratch).
__global__ __launch_bounds__(256) void k_conv3p(
    const float* __restrict__ h2, const float* __restrict__ w3,
    float* __restrict__ part3) {
  __shared__ float wlds[1536];          // [ci 16][co 8][12], wave w inits quarter w
  __shared__ float2 xbuf4[4][560];      // per-wave [8n][70 pad]; reused as handoff buf
  const int bx = blockIdx.x;
  const int kc = bx & 15;
  const int rbx = bx >> 4;
  const int cg = rbx % 48;
  const int nh = rbx / 48;              // 0..1
  const int co0 = cg * 8, ci0 = kc * 16, n0 = nh * 8;
  const int tid = threadIdx.x;          // 256
  const int wvid = tid >> 6;            // wave 0..3
  const int lane = tid & 63;
  // each wave inits ITS quarter of wlds (ci wvid*4..+3)
  #pragma unroll
  for (int k = 0; k < 6; ++k) {
    const int f = wvid * 384 + lane + k * 64;
    const int cil = f / 96, rem = f - cil * 96, c = rem / 12, kk = rem - c * 12;
    wlds[f] = w3[(co0 + c) * 3072 + (ci0 + cil) * 12 + kk];
  }
  const int n = lane >> 3, co = lane & 7;

  int s_lds[9], s_g[9];
  const bool v9 = lane < 40;
  #pragma unroll
  for (int k = 0; k < 9; ++k) {
    const int f = lane + k * 64;
    const int nn = f / 69, j = f - nn * 69;
    s_lds[k] = nn * 70 + j;
    s_g[k]   = (n0 + nn) * 17664 + j;   // + ci*69 at load
  }
  const float2* h2v = (const float2*)h2;
  const int cibase = ci0 + wvid * 4;

  float acc[42];
  #pragma unroll
  for (int i = 0; i < 42; ++i) acc[i] = 0.f;

  float2 r[9];
  #pragma unroll
  for (int k = 0; k < 8; ++k) r[k] = h2v[s_g[k] + cibase * 69];
  if (v9) r[8] = h2v[s_g[8] + cibase * 69];

  const float2* xrow2 = xbuf4[wvid] + n * 70;
  const float4* wl4 = (const float4*)wlds;

  #pragma unroll 1
  for (int cil = 0; cil < 4; ++cil) {
    #pragma unroll
    for (int k = 0; k < 8; ++k) xbuf4[wvid][s_lds[k]] = r[k];
    if (v9) xbuf4[wvid][s_lds[8]] = r[8];
    if (cil + 1 < 4) {
      #pragma unroll
      for (int k = 0; k < 8; ++k) r[k] = h2v[s_g[k] + (cibase + cil + 1) * 69];
      if (v9) r[8] = h2v[s_g[8] + (cibase + cil + 1) * 69];
    }
    const int cl = wvid * 4 + cil;
    const float4 w0 = wl4[(cl * 8 + co) * 3];
    const float4 w1 = wl4[(cl * 8 + co) * 3 + 1];
    const float4 w2q = wl4[(cl * 8 + co) * 3 + 2];
    const float wv[12] = {w0.x, w0.y, w0.z, w0.w, w1.x, w1.y,
                          w1.z, w1.w, w2q.x, w2q.y, w2q.z, w2q.w};
    float xf[30];
    #pragma unroll
    for (int t = 0; t < 15; ++t) {
      const float2 q = xrow2[t];
      xf[2 * t + 0] = q.x; xf[2 * t + 1] = q.y;
    }
    #pragma unroll
    for (int hot = 0; hot < 7; ++hot) {
      #pragma unroll
      for (int h = 0; h < 3; ++h)
        #pragma unroll
        for (int wo = 0; wo < 2; ++wo) {
          float e0  = xf[(2 * h + 0) * 3 + wo]     - wv[0];
          float e1  = xf[(2 * h + 0) * 3 + wo + 1] - wv[1];
          float e2  = xf[(2 * h + 1) * 3 + wo]     - wv[2];
          float e3  = xf[(2 * h + 1) * 3 + wo + 1] - wv[3];
          float e4  = xf[(2 * h + 2) * 3 + wo]     - wv[4];
          float e5  = xf[(2 * h + 2) * 3 + wo + 1] - wv[5];
          float e6  = xf[(2 * h + 3) * 3 + wo]     - wv[6];
          float e7  = xf[(2 * h + 3) * 3 + wo + 1] - wv[7];
          float e8  = xf[(2 * h + 4) * 3 + wo]     - wv[8];
          float e9  = xf[(2 * h + 4) * 3 + wo + 1] - wv[9];
          float e10 = xf[(2 * h + 5) * 3 + wo]     - wv[10];
          float e11 = xf[(2 * h + 5) * 3 + wo + 1] - wv[11];
          const float t0 = absadd(e0, e1);
          const float t1 = absadd(e2, e3);
          const float t2 = absadd(e4, e5);
          const float t3 = absadd(e6, e7);
          const float t4 = absadd(e8, e9);
          const float t5 = absadd(e10, e11);
          acc[(3 * hot + h) * 2 + wo] += ((t0 + t1) + (t2 + t3)) + (t4 + t5);
        }
      if (hot < 6) {
        #pragma unroll
        for (int t = 0; t < 12; ++t) xf[t] = xf[t + 18];
        #pragma unroll
        for (int t = 0; t < 9; ++t) {
          const float2 q = xrow2[9 * hot + 15 + t];
          xf[12 + 2 * t] = q.x; xf[13 + 2 * t] = q.y;
        }
      }
    }
  }
  // cross-wave reduction reusing xbuf4 region: 2 chunks of 21, FULLY UNROLLED
  __syncthreads();                      // all waves done with xbuf
  float* accb = (float*)xbuf4;          // 3 regions x 64 lanes x 22 floats = 16896 B
  #pragma unroll
  for (int chunk = 0; chunk < 2; ++chunk) {
    if (wvid > 0) {
      #pragma unroll
      for (int i = 0; i < 21; ++i)
        accb[((wvid - 1) * 64 + lane) * 22 + i] = acc[chunk * 21 + i];
    }
    __syncthreads();
    if (wvid == 0) {
      #pragma unroll
      for (int w = 0; w < 3; ++w)
        #pragma unroll
        for (int i = 0; i < 21; ++i)
          acc[chunk * 21 + i] += accb[(w * 64 + lane) * 22 + i];
    }
    __syncthreads();
  }
  if (wvid == 0) {
    float2* dst = (float2*)(part3 + (size_t)(kc * 384 + co0 + co) * 672 + (n0 + n) * 42);
    #pragma unroll
    for (int k = 0; k < 21; ++k) dst[k] = make_float2(acc[2 * k], acc[2 * k + 1]);
  }
}

// ---------------- Layer 3 combine: sum 16 K-partials, BN stats + apply -> h3(16,384,21,2)
__global__ __launch_bounds__(384) void k_combine3(
    const float* __restrict__ part3, const float* __restrict__ g3,
    const float* __restrict__ b3, float* __restrict__ h3) {
  const int co = blockIdx.x;    // 384
  const int tid = threadIdx.x;  // 384, active 336, 2 pos each
  const bool active = tid < 336;
  float v[2];
  double s = 0.0, sq = 0.0;
  #pragma unroll
  for (int k = 0; k < 2; ++k) {
    float sum = 0.f;
    if (active) {
      const int p = tid + k * 336;
      #pragma unroll
      for (int kc = 0; kc < 16; ++kc)
        sum += part3[(size_t)(kc * 384 + co) * 672 + p];
    }
    const float val = -sum;
    v[k] = val;
    if (active) { s += (double)val; sq += (double)val * (double)val; }
  }
  block_reduce_2d<6>(s, sq);
  __shared__ float ssc, ssh;
  if (tid == 0) {
    const double mean = s * (1.0 / 672.0);
    const double var  = sq * (1.0 / 672.0) - mean * mean;
    const float rstd = (float)rsqrt(var + 1e-5);
    const float sc = g3[co] * rstd;
    ssc = sc;
    ssh = b3[co] - (float)mean * sc;
  }
  __syncthreads();
  if (active) {
    const float sc = ssc, sh = ssh;
    #pragma unroll
    for (int k = 0; k < 2; ++k) {
      const int p = tid + k * 336;
      const int n = p / 42, rem = p - n * 42;
      h3[n * 16128 + co * 42 + rem] = fmaxf(0.f, fmaf(v[k], sc, sh));
    }
  }
}

// ---------------- FC partial: h3(16,16128) @ Wfc(6,16128)^T, K split 4 ways
__global__ __launch_bounds__(256) void k_fcp(
    const float* __restrict__ h3, const float* __restrict__ Wfc,
    float* __restrict__ hfcp) {
  const int bx = blockIdx.x;    // 384 = 96 pairs x 4
  const int pair = bx >> 2, q = bx & 3;
  const int n = pair / 6, o = pair - n * 6;
  const float4* xr = (const float4*)(h3 + n * 16128) + q * 1008;
  const float4* wr = (const float4*)(Wfc + o * 16128) + q * 1008;
  float sacc = 0.f;
  for (int k = threadIdx.x; k < 1008; k += 256) {
    const float4 xv = xr[k];
    const float4 wv = wr[k];
    sacc += xv.x * wv.x + xv.y * wv.y + xv.z * wv.z + xv.w * wv.w;
  }
  double d = (double)sacc, dummy = 0.0;
  block_reduce_2d<4>(d, dummy);
  if (threadIdx.x == 0) hfcp[bx] = (float)d;
}

// ---------------- Final: sum FC partials + bias, LayerNorm over 96, per-row L2 norm -> out(16,6)
__global__ __launch_bounds__(128) void k_final(
    const float* __restrict__ hfcp, const float* __restrict__ bfc,
    float* __restrict__ out) {
  __shared__ float ys[96];
  __shared__ float params[2];
  const int tid = threadIdx.x;
  float v = 0.f;
  if (tid < 96) {
    v = hfcp[tid * 4 + 0] + hfcp[tid * 4 + 1] + hfcp[tid * 4 + 2] + hfcp[tid * 4 + 3]
        + bfc[tid % 6];
    ys[tid] = v;
  }
  __syncthreads();
  if (tid == 0) {
    double s = 0.0, sq = 0.0;
    for (int i = 0; i < 96; ++i) { const double t = (double)ys[i]; s += t; sq += t * t; }
    const double mu = s / 96.0;
    const double var = sq / 96.0 - mu * mu;
    params[0] = (float)mu;
    params[1] = (float)rsqrt(var + 1e-5);
  }
  __syncthreads();
  const float y = (v - params[0]) * params[1];
  __syncthreads();
  if (tid < 96) ys[tid] = y;
  __syncthreads();
  if (tid < 96) {
    const int n = tid / 6;
    float ss = 0.f;
    #pragma unroll
    for (int k = 0; k < 6; ++k) { const float t = ys[n * 6 + k]; ss += t * t; }
    const float norm = sqrtf(ss);
    out[tid] = y / fmaxf(norm, 1e-12f);
  }
}

extern "C" void kernel_launch(void* const* d_in, const int* in_sizes, int n_in,
                              void* d_out, int out_size, void* d_ws, size_t ws_size,
                              hipStream_t stream) {
  const float* x   = (const float*)d_in[0];
  const float* w1  = (const float*)d_in[1];
  const float* g1  = (const float*)d_in[2];
  const float* b1  = (const float*)d_in[3];
  const float* w2  = (const float*)d_in[4];
  const float* g2  = (const float*)d_in[5];
  const float* b2  = (const float*)d_in[6];
  const float* w3  = (const float*)d_in[7];
  const float* g3  = (const float*)d_in[8];
  const float* b3  = (const float*)d_in[9];
  const float* Wfc = (const float*)d_in[10];
  const float* bfc = (const float*)d_in[11];

  float* ws   = (float*)d_ws;
  float* h1   = ws;                 // 589824
  float* h2   = h1 + 589824;        // 565248
  float* h3   = h2 + 565248;        // 258048
  float* hfcp = h3 + 258048;        // 384
  float* part = hfcp + 384;         // max(8*256*2208, 16*384*672) = 4521984
  float* out  = (float*)d_out;

  k_conv1   <<<128, 256, 0, stream>>>(x, w1, g1, b1, h1);
  k_conv2p  <<<1024, 256, 0, stream>>>(h1, w2, part);
  k_combine2<<<256, 384, 0, stream>>>(part, g2, b2, h2);
  k_conv3p  <<<1536, 256, 0, stream>>>(h2, w3, part);
  k_combine3<<<384, 384, 0, stream>>>(part, g3, b3, h3);
  k_fcp     <<<384, 256, 0, stream>>>(h3, Wfc, hfcp);
  k_final   <<<1, 128, 0, stream>>>(hfcp, bfc, out);
}